// Round 2
// baseline (265.578 us; speedup 1.0000x reference)
//
#include <hip/hip_runtime.h>

#define IN_F   4096
#define OUT_F  11008
#define BATCH  16
#define CO     16              // output channels per block (4 waves x 4 rows)
#define BLOCK  256
#define STAGE  512             // k staged per LDS buffer
#define NST    (IN_F / STAGE)  // 8 stages, double-buffered

typedef int   i32x4 __attribute__((ext_vector_type(4)));

// Single kernel, no split-K, no atomics, no init pass.
// Block bx: 16 output channels [bx*16 .. bx*16+16), full K = 4096.
// Wave ty owns rows o0..o0+3. Lane tx covers k = {tx*4..tx*4+3} + 256*it.
// x is staged in a double-buffered [2][16][512] LDS tile (2 x 32 KB); one
// barrier per 512-k stage (measured neutral vs barrier-free in R0/R1).
// Epilogue: in-place wave butterfly, then ONE direct store per lane of
// bias[o] + scale[o]*partial -- 688 blocks x 256 lanes exactly cover out.
//
// R1 rationale: R0 showed barrier/vmcnt structure is NOT the limiter; the
// remaining controllable costs were the init kernel launch and 704K fp32
// atomicAdds from SPLITK=4. Dropping split-K costs only ~1-2 us of tail
// (688 blocks sharing HBM) and removes both.
__global__ __launch_bounds__(BLOCK) void qlin_kernel(
    const float* __restrict__ x,      // [16, 4096]
    const int*   __restrict__ w,      // [11008, 4096] int8 values in int32
    const float* __restrict__ scale,  // [11008]
    const float* __restrict__ bias,   // [11008]
    float* __restrict__ out)          // [16, 11008]
{
    __shared__ float xs[2][BATCH][STAGE];   // 64 KB -> 2 blocks/CU

    const int tid = threadIdx.x;
    const int tx  = tid & 63;
    const int ty  = tid >> 6;
    const int o0  = blockIdx.x * CO + ty * 4;

    const i32x4* __restrict__ wbase = (const i32x4*)(w + (size_t)o0 * IN_F);

    float acc[64];
    #pragma unroll
    for (int i = 0; i < 64; ++i) acc[i] = 0.f;

    // ---- async global->LDS stage of x[16][s*512 .. s*512+512) into buf ----
    // f = float4 slot; LDS byte addr = buf base + f*16 = wave-uniform + lane*16.
    auto stage_load = [&](int s, int buf) {
        #pragma unroll
        for (int j = 0; j < (BATCH * STAGE / 4) / BLOCK; ++j) {   // 8 per thread
            int f  = tid + j * BLOCK;
            int b  = f >> 7;                  // STAGE/4 = 128 float4 per row
            int kc = f & 127;
            const float* src = x + (size_t)b * IN_F + s * STAGE + kc * 4;
            void* dst = (char*)&xs[buf][0][0] + (size_t)f * 16;
            __builtin_amdgcn_global_load_lds(
                (const __attribute__((address_space(1))) void*)src,
                (__attribute__((address_space(3))) void*)dst,
                16, 0, 0);
        }
    };

    stage_load(0, 0);
    __syncthreads();   // buf 0 resident

    for (int s = 0; s < NST; ++s) {
        const int cur = s & 1;
        if (s + 1 < NST) stage_load(s + 1, cur ^ 1);   // in flight under compute

        // ---- weights for this stage: 2 its x 4 rows, stream-once ----
        i32x4 wr[2][4];
        #pragma unroll
        for (int it = 0; it < 2; ++it) {
            const size_t kg4 = (size_t)(s * 128 + it * 64 + tx);
            #pragma unroll
            for (int r = 0; r < 4; ++r)
                wr[it][r] = __builtin_nontemporal_load(wbase + kg4 + (size_t)r * (IN_F / 4));
        }

        #pragma unroll
        for (int it = 0; it < 2; ++it) {
            const int kl = it * 256 + tx * 4;   // k within stage

            float wf[4][4];
            #pragma unroll
            for (int r = 0; r < 4; ++r)
                #pragma unroll
                for (int e = 0; e < 4; ++e)
                    wf[r][e] = (float)wr[it][r][e];

            // batches in chunks of 4 to bound live float4 registers
            #pragma unroll
            for (int bc = 0; bc < 4; ++bc) {
                float4 xv[4];
                #pragma unroll
                for (int bb = 0; bb < 4; ++bb)
                    xv[bb] = *(const float4*)&xs[cur][bc * 4 + bb][kl];

                #pragma unroll
                for (int r = 0; r < 4; ++r)
                    #pragma unroll
                    for (int bb = 0; bb < 4; ++bb) {
                        float a = acc[r * 16 + bc * 4 + bb];
                        a += wf[r][0] * xv[bb].x;
                        a += wf[r][1] * xv[bb].y;
                        a += wf[r][2] * xv[bb].z;
                        a += wf[r][3] * xv[bb].w;
                        acc[r * 16 + bc * 4 + bb] = a;
                    }
            }
        }

        // Drains vmcnt -> next buf resident; also fences xs[cur] reads before
        // iteration s+1 re-issues loads into it (targets buf cur at s+1).
        __syncthreads();
    }

    // ---- in-place folding butterfly across 64 lanes ----
    // After folding, lane tx holds the full partial for flat index tx = r*16+b.
    #pragma unroll
    for (int wd = 32; wd >= 1; wd >>= 1) {
        const bool upper = (tx & wd) != 0;
        #pragma unroll
        for (int i = 0; i < wd; ++i) {
            float lo = acc[i]      + __shfl_xor(acc[i],      wd);
            float hi = acc[i + wd] + __shfl_xor(acc[i + wd], wd);
            acc[i] = upper ? hi : lo;
        }
    }

    const int o = o0 + (tx >> 4);
    const int b = tx & 15;
    out[(size_t)b * OUT_F + o] = fmaf(acc[0], scale[o], bias[o]);
}

extern "C" void kernel_launch(void* const* d_in, const int* in_sizes, int n_in,
                              void* d_out, int out_size, void* d_ws, size_t ws_size,
                              hipStream_t stream) {
    const float* x     = (const float*)d_in[0];
    const int*   w     = (const int*)d_in[1];
    const float* scale = (const float*)d_in[2];
    const float* bias  = (const float*)d_in[3];
    float* out = (float*)d_out;

    qlin_kernel<<<dim3(OUT_F / CO), dim3(BLOCK), 0, stream>>>(x, w, scale, bias, out);
}

// Round 4
// 260.902 us; speedup vs baseline: 1.0179x; 1.0179x over previous
//
#include <hip/hip_runtime.h>

#define IN_F   4096
#define OUT_F  11008
#define BATCH  16
#define CO     16              // output channels per block (4 waves x 4 rows)
#define BLOCK  256
#define SPLITK 4
#define KCHUNK (IN_F / SPLITK)   // 1024 k per block
#define STAGE  256               // k per LDS buffer (one lane-pass: 64 lanes x 4)
#define NST    (KCHUNK / STAGE)  // 4 stages per block, double-buffered

typedef int   i32x4 __attribute__((ext_vector_type(4)));

// out[b][o] = bias[o]  (pre-init so main kernel can atomicAdd partials)
__global__ __launch_bounds__(BLOCK) void init_out_kernel(
    const float* __restrict__ bias, float* __restrict__ out)
{
    int idx = blockIdx.x * BLOCK + threadIdx.x;
    if (idx < BATCH * OUT_F) {
        int o = idx % OUT_F;
        out[idx] = bias[o];
    }
}

// R4 = R3 with the weight-index bug fixed.
// R3 computed kg4 with a stray *4 (s*256 i32x4 instead of s*64), which both
// mis-addressed the stream and ran past the end of w for the last rows at
// kb=3072 -> memory fault -> core dump. Correct advance: (kb + s*STAGE)/4.
//
// Design (unchanged from R3):
//   - SPLITK=4 grid (2752 blocks): R0's empirically-best config.
//   - [2][16][256] = 32 KB LDS double-buffer + __launch_bounds__(256,3):
//     3 blocks/CU (12 waves) vs R1/R2's 2 blocks/CU -> +50% loads in flight
//     for the 180 MB weight stream (floor ~29 us @ 6.3 TB/s).
//   - Per stage: weight loads issued FIRST, then next-stage x prefetch, so
//     the first FMA waits at vmcnt(4) (weights only) and the prefetch drain
//     hides under compute.
__global__ __launch_bounds__(BLOCK, 3) void qlin_kernel(
    const float* __restrict__ x,      // [16, 4096]
    const int*   __restrict__ w,      // [11008, 4096] int8 values in int32
    const float* __restrict__ scale,  // [11008]
    float* __restrict__ out)          // [16, 11008], pre-filled with bias
{
    __shared__ float xs[2][BATCH][STAGE];   // 32 KB

    const int tid = threadIdx.x;
    const int tx  = tid & 63;
    const int ty  = tid >> 6;
    const int o0  = blockIdx.x * CO + ty * 4;
    const int kb  = blockIdx.y * KCHUNK;

    const i32x4* __restrict__ wbase = (const i32x4*)(w + (size_t)o0 * IN_F);

    float acc[64];
    #pragma unroll
    for (int i = 0; i < 64; ++i) acc[i] = 0.f;

    // ---- async global->LDS stage of x[16][kb+s*256 .. +256) into buf ----
    // f = float4 slot; LDS byte addr = buf base + f*16 (linear, wave-uniform
    // base + lane*16 as global_load_lds requires).
    auto stage_load = [&](int s, int buf) {
        #pragma unroll
        for (int j = 0; j < (BATCH * STAGE / 4) / BLOCK; ++j) {   // 4 per thread
            int f  = tid + j * BLOCK;
            int b  = f >> 6;                  // STAGE/4 = 64 float4 per row
            int kc = f & 63;
            const float* src = x + (size_t)b * IN_F + kb + s * STAGE + kc * 4;
            void* dst = (char*)&xs[buf][0][0] + (size_t)f * 16;
            __builtin_amdgcn_global_load_lds(
                (const __attribute__((address_space(1))) void*)src,
                (__attribute__((address_space(3))) void*)dst,
                16, 0, 0);
        }
    };

    stage_load(0, 0);
    __syncthreads();   // buf 0 resident

    for (int s = 0; s < NST; ++s) {
        const int cur = s & 1;

        // ---- weights for this stage: 4 rows x 16B/lane, stream-once ----
        // k range [kb + s*STAGE, +256); i32x4 index = (kb + s*STAGE)/4 + tx.
        const size_t kg4 = (size_t)((kb + s * STAGE) >> 2) + tx;
        i32x4 wr[4];
        #pragma unroll
        for (int r = 0; r < 4; ++r)
            wr[r] = __builtin_nontemporal_load(wbase + kg4 + (size_t)r * (IN_F / 4));

        if (s + 1 < NST) stage_load(s + 1, cur ^ 1);   // in flight under compute

        float wf[4][4];
        #pragma unroll
        for (int r = 0; r < 4; ++r)
            #pragma unroll
            for (int e = 0; e < 4; ++e)
                wf[r][e] = (float)wr[r][e];

        const int kl = tx * 4;   // k within stage (64 lanes x 4 = 256)

        // batches in chunks of 4 to bound live float4 registers
        #pragma unroll
        for (int bc = 0; bc < 4; ++bc) {
            float4 xv[4];
            #pragma unroll
            for (int bb = 0; bb < 4; ++bb)
                xv[bb] = *(const float4*)&xs[cur][bc * 4 + bb][kl];

            #pragma unroll
            for (int r = 0; r < 4; ++r)
                #pragma unroll
                for (int bb = 0; bb < 4; ++bb) {
                    float a = acc[r * 16 + bc * 4 + bb];
                    a += wf[r][0] * xv[bb].x;
                    a += wf[r][1] * xv[bb].y;
                    a += wf[r][2] * xv[bb].z;
                    a += wf[r][3] * xv[bb].w;
                    acc[r * 16 + bc * 4 + bb] = a;
                }
        }

        // Drains vmcnt -> next buf resident; also fences xs[cur] reads before
        // stage s+1 prefetch re-targets buf cur.
        __syncthreads();
    }

    // ---- in-place folding butterfly across 64 lanes ----
    // After folding, lane tx holds the full partial for flat index tx = r*16+b.
    #pragma unroll
    for (int wd = 32; wd >= 1; wd >>= 1) {
        const bool upper = (tx & wd) != 0;
        #pragma unroll
        for (int i = 0; i < wd; ++i) {
            float lo = acc[i]      + __shfl_xor(acc[i],      wd);
            float hi = acc[i + wd] + __shfl_xor(acc[i + wd], wd);
            acc[i] = upper ? hi : lo;
        }
    }

    const int o = o0 + (tx >> 4);
    const int b = tx & 15;
    atomicAdd(&out[(size_t)b * OUT_F + o], acc[0] * scale[o]);
}

extern "C" void kernel_launch(void* const* d_in, const int* in_sizes, int n_in,
                              void* d_out, int out_size, void* d_ws, size_t ws_size,
                              hipStream_t stream) {
    const float* x     = (const float*)d_in[0];
    const int*   w     = (const int*)d_in[1];
    const float* scale = (const float*)d_in[2];
    const float* bias  = (const float*)d_in[3];
    float* out = (float*)d_out;

    init_out_kernel<<<(BATCH * OUT_F + BLOCK - 1) / BLOCK, BLOCK, 0, stream>>>(bias, out);

    dim3 grid(OUT_F / CO, SPLITK);   // 688 x 4 = 2752 blocks
    qlin_kernel<<<grid, dim3(BLOCK), 0, stream>>>(x, w, scale, out);
}